// Round 13
// baseline (648.957 us; speedup 1.0000x reference)
//
#include <hip/hip_runtime.h>
#include <stdint.h>

// ---------- types ----------
typedef __attribute__((ext_vector_type(8))) short bf16x8;
typedef __attribute__((ext_vector_type(4))) float f32x4;
typedef __attribute__((ext_vector_type(8))) unsigned short u16x8;
typedef __attribute__((ext_vector_type(4))) unsigned short u16x4;
typedef __attribute__((address_space(3))) uint32_t as3_u32;
typedef const __attribute__((address_space(1))) uint32_t as1_u32;

#define DEV __device__ __forceinline__

DEV float bf2f(unsigned short u) {
    union { unsigned int i; float f; } x; x.i = ((unsigned int)u) << 16; return x.f;
}
DEV unsigned short f2bf(float f) {
    union { float f; unsigned int i; } x; x.f = f;
    unsigned int i = x.i;
    return (unsigned short)((i + 0x7FFFu + ((i >> 16) & 1u)) >> 16);  // RNE, no NaN in data
}

// ---------- fused prep: x->bf16 convert, LoRA-folded weight transposes, bias concat ----------
// type 0: flat f32->bf16 convert
// type 2: qkv bias concat
// type 3: fold-transpose  dst[c][r] = bf16( src[r][c] + sum_j a[r][j]*bb[j][c] )
struct PrepDesc {
    const float* src; const float* a; const float* bb; unsigned short* dst;
    int R, C, ds, gx, base, type;
};
struct PrepArgs {
    PrepDesc d[10]; int nd;
    const float* bq; const float* bk; const float* bv; float* bias_out;
};

__global__ __launch_bounds__(256) void k_prep(PrepArgs A) {
    __shared__ float t[32][33];
    __shared__ float aL[32][17];
    __shared__ float bbL[16][33];
    int b = blockIdx.x, tid = threadIdx.x;
    int i = 0;
    while (i + 1 < A.nd && A.d[i + 1].base <= b) i++;
    PrepDesc d = A.d[i];
    int local = b - d.base;
    if (d.type == 0) {
        size_t idx = (size_t)local * 256 + tid;
        const float4* p = (const float4*)(d.src + idx * 8);
        float4 a = p[0], c = p[1];
        u16x8 o;
        o[0] = f2bf(a.x); o[1] = f2bf(a.y); o[2] = f2bf(a.z); o[3] = f2bf(a.w);
        o[4] = f2bf(c.x); o[5] = f2bf(c.y); o[6] = f2bf(c.z); o[7] = f2bf(c.w);
        *(u16x8*)(d.dst + idx * 8) = o;
    } else if (d.type == 3) {
        int bx = local % d.gx, by = local / d.gx;
        int c0 = bx * 32, r0 = by * 32;
        int tx = tid & 31, ty = tid >> 5;
#pragma unroll
        for (int k = 0; k < 4; k++) {
            int r = r0 + ty + k * 8, c = c0 + tx;
            t[ty + k * 8][tx] = (r < d.R && c < d.C) ? d.src[(size_t)r * d.C + c] : 0.f;
        }
        {
            int idx = tid * 2;
            int i0 = idx >> 4, j0 = idx & 15;
            aL[i0][j0] = (r0 + i0 < d.R) ? d.a[(size_t)(r0 + i0) * 16 + j0] : 0.f;
            int idx1 = idx + 1;
            int i1 = idx1 >> 4, j1 = idx1 & 15;
            aL[i1][j1] = (r0 + i1 < d.R) ? d.a[(size_t)(r0 + i1) * 16 + j1] : 0.f;
        }
        {
            int idx = tid * 2;
            int j0 = idx >> 5, i0 = idx & 31;
            bbL[j0][i0] = (c0 + i0 < d.C) ? d.bb[(size_t)j0 * d.C + c0 + i0] : 0.f;
            int idx1 = idx + 1;
            int j1 = idx1 >> 5, i1 = idx1 & 31;
            bbL[j1][i1] = (c0 + i1 < d.C) ? d.bb[(size_t)j1 * d.C + c0 + i1] : 0.f;
        }
        __syncthreads();
#pragma unroll
        for (int k = 0; k < 4; k++) {
            int c = c0 + ty + k * 8, r = r0 + tx;
            if (c < d.C && r < d.R) {
                float acc = t[tx][ty + k * 8];
#pragma unroll
                for (int j = 0; j < 16; j++) acc += aL[tx][j] * bbL[j][ty + k * 8];
                d.dst[(size_t)c * d.ds + r] = f2bf(acc);
            }
        }
    } else {
        int idx = local * 256 + tid;
        if (idx < 3072)
            A.bias_out[idx] = (idx < 1024) ? A.bq[idx]
                            : (idx < 2048) ? A.bk[idx - 1024] : A.bv[idx - 2048];
    }
}

// ---------- main GEMM (m97-style SINGLE-buffered, 128x128, 4 waves, 5 blocks/CU):
// C = A@B'^T + bias (+res)(gelu?)   [LoRA pre-folded into B']
// r13: epilogue bounce uses chunk-XOR [128][128] (not pad-136) -> LDS exactly 32768 B
// -> 5 blocks/CU (160KiB/32KB). XCD swizzle SHAPE-CONDITIONAL (r6): swz only if gridDim.x<=8.
struct GemmArgs {
    const unsigned short* A;    // [M][K] bf16
    const unsigned short* B;    // [N][K] bf16 (pre-transposed, LoRA-folded weight)
    const float* bias;          // [N]
    const float* res;           // [M][N] f32 (RES==1)
    const unsigned short* resb; // [M][N] bf16 (RES==2)
    float* outf;                // OUTB==false
    unsigned short* outb;       // OUTB==true
    int M, N, K, swz;
};

template <int RES, bool GELU, bool OUTB>
__global__ __launch_bounds__(256, 5) void k_gemm(GemmArgs P) {
    __shared__ __align__(128) unsigned short smem[16384];  // 32768 B: main A|B; epilogue 128x128 swz
    int tid = threadIdx.x, l = tid & 63, w = tid >> 6;
    int wm = w >> 1, wn = w & 1, lr = l & 15, g = l >> 4, h3 = l & 7;

    // ---- block mapping ----
    int n0, m0;
    if (P.swz) {
        int nwg = gridDim.x * gridDim.y;
        int lin = blockIdx.y * gridDim.x + blockIdx.x;
        int wg = (lin & 7) * (nwg >> 3) + (lin >> 3);
        n0 = (wg % gridDim.x) * 128; m0 = (wg / gridDim.x) * 128;
    } else {
        n0 = blockIdx.x * 128; m0 = blockIdx.y * 128;
    }

    // per-lane staging sources (pre-swizzled global chunk: LDS slot (r,p) holds chunk c = p^(r&7))
    const unsigned short* pa[4];
    const unsigned short* pb[4];
#pragma unroll
    for (int i = 0; i < 4; i++) {
        int idx = i * 256 + w * 64 + l;
        int r = idx >> 3, p = idx & 7, cc = p ^ (r & 7);
        pa[i] = P.A + (size_t)(m0 + r) * P.K + cc * 8;
        pb[i] = P.B + (size_t)(n0 + r) * P.K + cc * 8;
    }
    f32x4 acc[4][4];
#pragma unroll
    for (int a = 0; a < 4; a++)
#pragma unroll
        for (int b = 0; b < 4; b++) acc[a][b] = (f32x4){0.f, 0.f, 0.f, 0.f};

    int KT = P.K >> 6;
    for (int kt = 0; kt < KT; kt++) {
#pragma unroll
        for (int i = 0; i < 4; i++) {
            unsigned int base = i * 2048 + w * 512;  // ushort elems, uniform per wave
            __builtin_amdgcn_global_load_lds((as1_u32*)(pa[i] + kt * 64),
                                             (as3_u32*)(smem + base), 16, 0, 0);
            __builtin_amdgcn_global_load_lds((as1_u32*)(pb[i] + kt * 64),
                                             (as3_u32*)(smem + base + 8192), 16, 0, 0);
        }
        __syncthreads();
        const unsigned short* bufA = smem;
        const unsigned short* bufB = smem + 8192;
#pragma unroll
        for (int ks = 0; ks < 2; ks++) {
            bf16x8 af[4], bfr[4];
#pragma unroll
            for (int mi = 0; mi < 4; mi++) {
                int row = wm * 64 + mi * 16 + lr;
                af[mi] = *(const bf16x8*)(bufA + row * 64 + (((ks * 4 + g) ^ h3) * 8));
            }
#pragma unroll
            for (int ni = 0; ni < 4; ni++) {
                int row = wn * 64 + ni * 16 + lr;
                bfr[ni] = *(const bf16x8*)(bufB + row * 64 + (((ks * 4 + g) ^ h3) * 8));
            }
#pragma unroll
            for (int mi = 0; mi < 4; mi++)
#pragma unroll
                for (int ni = 0; ni < 4; ni++)
                    acc[mi][ni] = __builtin_amdgcn_mfma_f32_16x16x32_bf16(af[mi], bfr[ni],
                                                                          acc[mi][ni], 0, 0, 0);
        }
        __syncthreads();
    }

    if constexpr (OUTB) {
        // ---- bf16 output: bias (+res) (+gelu), chunk-XOR swizzled LDS bounce, coalesced out ----
        unsigned short* eb = smem;   // [128][128] bf16, chunk p of row m at p^(m&7)
#pragma unroll
        for (int ni = 0; ni < 4; ni++) {
            int nn = wn * 64 + ni * 16 + lr;
            float bv = P.bias[n0 + nn];
#pragma unroll
            for (int mi = 0; mi < 4; mi++) {
#pragma unroll
                for (int r = 0; r < 4; r++) {
                    int mm = wm * 64 + mi * 16 + g * 4 + r;
                    float v = acc[mi][ni][r] + bv;
                    if constexpr (RES == 1) v += P.res[(size_t)(m0 + mm) * P.N + n0 + nn];
                    if constexpr (RES == 2) v += bf2f(P.resb[(size_t)(m0 + mm) * P.N + n0 + nn]);
                    if constexpr (GELU) {
                        float u = 0.7978845608f * v * (1.f + 0.044715f * v * v);
                        float e = __expf(2.f * u);
                        v = v - v / (e + 1.f);
                    }
                    eb[mm * 128 + (((nn >> 3) ^ (mm & 7)) * 8) + (nn & 7)] = f2bf(v);
                }
            }
        }
        __syncthreads();
#pragma unroll
        for (int i = 0; i < 8; i++) {
            int idx = i * 256 + tid;
            int row = idx >> 4, c = idx & 15;
            u16x8 d = *(const u16x8*)(eb + row * 128 + ((c ^ (row & 7)) * 8));
            *(u16x8*)(P.outb + (size_t)(m0 + row) * P.N + n0 + c * 8) = d;
        }
    } else {
        // ---- f32 output (+res): direct stores ----
#pragma unroll
        for (int ni = 0; ni < 4; ni++) {
            int n = n0 + wn * 64 + ni * 16 + lr;
            float bv = P.bias[n];
#pragma unroll
            for (int mi = 0; mi < 4; mi++) {
#pragma unroll
                for (int r = 0; r < 4; r++) {
                    int m = m0 + wm * 64 + mi * 16 + g * 4 + r;
                    float v = acc[mi][ni][r] + bv;
                    if constexpr (RES == 1) v += P.res[(size_t)m * P.N + n];
                    if constexpr (RES == 2) v += bf2f(P.resb[(size_t)m * P.N + n]);
                    P.outf[(size_t)m * P.N + n] = v;
                }
            }
        }
    }
}

// ---------- flash attention: qkv [8192][3072] bf16 -> o [8192][1024] bf16 ----------
__global__ __launch_bounds__(256) void k_attn(const unsigned short* __restrict__ qkv,
                                              const float* __restrict__ mask,
                                              unsigned short* __restrict__ o) {
    __shared__ __align__(128) unsigned short Kl[64 * 64];
    __shared__ __align__(128) unsigned short Vt[64 * 64];
    __shared__ __align__(128) unsigned short Pl[4 * 16 * 64];
    int tid = threadIdx.x, l = tid & 63, w = tid >> 6;
    int b = blockIdx.y >> 4, h = blockIdx.y & 15;
    int qbase = blockIdx.x * 64;
    int lr = l & 15, g = l >> 4, h3 = l & 7;

    size_t rowQ = (size_t)(b * 512 + qbase + w * 16 + lr) * 3072 + h * 64;
    bf16x8 qf0 = *(const bf16x8*)(qkv + rowQ + g * 8);
    bf16x8 qf1 = *(const bf16x8*)(qkv + rowQ + 32 + g * 8);

    f32x4 oacc[4];
    float mrun[4], lrun[4];
#pragma unroll
    for (int i = 0; i < 4; i++) { oacc[i] = (f32x4){0.f, 0.f, 0.f, 0.f}; mrun[i] = -1e30f; lrun[i] = 0.f; }

    int sr = tid >> 3, sc = tid & 7;          // K staging
    int cV = tid & 7, kv0 = (tid >> 3) * 2;   // V staging (pairs)
    const unsigned short* kbase = qkv + (size_t)(b * 512) * 3072 + 1024 + h * 64;
    const unsigned short* vbase = qkv + (size_t)(b * 512) * 3072 + 2048 + h * 64;
    unsigned short* pw = Pl + w * 1024;

    for (int kt = 0; kt < 8; kt++) {
#pragma unroll
        for (int i = 0; i < 2; i++) {
            int r = sr + i * 32;
            u16x8 kd = *(const u16x8*)(kbase + (size_t)(kt * 64 + r) * 3072 + sc * 8);
            *(u16x8*)(Kl + r * 64 + ((sc ^ (r & 7)) * 8)) = kd;
        }
        {
            u16x8 v0 = *(const u16x8*)(vbase + (size_t)(kt * 64 + kv0) * 3072 + cV * 8);
            u16x8 v1 = *(const u16x8*)(vbase + (size_t)(kt * 64 + kv0 + 1) * 3072 + cV * 8);
            int kc = kv0 >> 3, ke = kv0 & 7;
#pragma unroll
            for (int j = 0; j < 8; j++) {
                int hd = cV * 8 + j;
                unsigned int pr = (unsigned int)v0[j] | ((unsigned int)v1[j] << 16);
                *(unsigned int*)(Vt + hd * 64 + ((kc ^ (hd & 7)) * 8) + ke) = pr;
            }
        }
        __syncthreads();

        f32x4 s[4];
#pragma unroll
        for (int i = 0; i < 4; i++) s[i] = (f32x4){0.f, 0.f, 0.f, 0.f};
#pragma unroll
        for (int ks = 0; ks < 2; ks++) {
            bf16x8 qa = ks ? qf1 : qf0;
#pragma unroll
            for (int nf = 0; nf < 4; nf++) {
                int kr = lr + nf * 16;
                bf16x8 kf = *(const bf16x8*)(Kl + kr * 64 + (((ks * 4 + g) ^ h3) * 8));
                s[nf] = __builtin_amdgcn_mfma_f32_16x16x32_bf16(qa, kf, s[nf], 0, 0, 0);
            }
        }
        const float* mrow = mask + b * 512 + kt * 64;
#pragma unroll
        for (int nf = 0; nf < 4; nf++) {
            float mk = mrow[lr + nf * 16];
            s[nf] = s[nf] * 0.125f + mk;
        }
        float mx[4];
#pragma unroll
        for (int r = 0; r < 4; r++) {
            mx[r] = fmaxf(fmaxf(s[0][r], s[1][r]), fmaxf(s[2][r], s[3][r]));
#pragma unroll
            for (int d = 1; d < 16; d <<= 1) mx[r] = fmaxf(mx[r], __shfl_xor(mx[r], d, 64));
        }
        float al[4];
#pragma unroll
        for (int r = 0; r < 4; r++) {
            float mn = fmaxf(mrun[r], mx[r]);
            al[r] = __expf(mrun[r] - mn);
            mrun[r] = mn;
        }
        float rs[4] = {0.f, 0.f, 0.f, 0.f};
#pragma unroll
        for (int nf = 0; nf < 4; nf++)
#pragma unroll
            for (int r = 0; r < 4; r++) {
                float p = __expf(s[nf][r] - mrun[r]);
                s[nf][r] = p;
                rs[r] += p;
            }
#pragma unroll
        for (int r = 0; r < 4; r++) {
#pragma unroll
            for (int d = 1; d < 16; d <<= 1) rs[r] += __shfl_xor(rs[r], d, 64);
            lrun[r] = lrun[r] * al[r] + rs[r];
        }
#pragma unroll
        for (int nh = 0; nh < 4; nh++) {
            f32x4 t = oacc[nh];
            t[0] *= al[0]; t[1] *= al[1]; t[2] *= al[2]; t[3] *= al[3];
            oacc[nh] = t;
        }
#pragma unroll
        for (int nf = 0; nf < 4; nf++) {
            int pc = lr + nf * 16;
#pragma unroll
            for (int r = 0; r < 4; r++) {
                int prr = g * 4 + r;
                pw[prr * 64 + (((pc >> 3) ^ (prr & 7)) * 8) + (pc & 7)] = f2bf(s[nf][r]);
            }
        }
#pragma unroll
        for (int ks = 0; ks < 2; ks++) {
            bf16x8 pa = *(const bf16x8*)(pw + lr * 64 + (((ks * 4 + g) ^ h3) * 8));
#pragma unroll
            for (int nh = 0; nh < 4; nh++) {
                int vr = lr + nh * 16;
                bf16x8 vf = *(const bf16x8*)(Vt + vr * 64 + (((ks * 4 + g) ^ h3) * 8));
                oacc[nh] = __builtin_amdgcn_mfma_f32_16x16x32_bf16(pa, vf, oacc[nh], 0, 0, 0);
            }
        }
        __syncthreads();
    }
#pragma unroll
    for (int r = 0; r < 4; r++) {
        float inv = 1.f / lrun[r];
        size_t orow = (size_t)(b * 512 + qbase + w * 16 + g * 4 + r) * 1024 + h * 64;
#pragma unroll
        for (int nh = 0; nh < 4; nh++)
            o[orow + lr + nh * 16] = f2bf(oacc[nh][r] * inv);
    }
}

// ---------- LayerNorm, bf16 in -> bf16 out (row = 1024) ----------
__global__ __launch_bounds__(256) void k_ln_b(const unsigned short* __restrict__ in,
                                              const float* __restrict__ gamma,
                                              const float* __restrict__ beta,
                                              unsigned short* __restrict__ outb) {
    int row = blockIdx.x, tid = threadIdx.x;
    u16x4 raw = *(const u16x4*)(in + (size_t)row * 1024 + tid * 4);
    float v0 = bf2f(raw[0]), v1 = bf2f(raw[1]), v2 = bf2f(raw[2]), v3 = bf2f(raw[3]);
    float s = v0 + v1 + v2 + v3;
    float q = v0 * v0 + v1 * v1 + v2 * v2 + v3 * v3;
#pragma unroll
    for (int d = 1; d < 64; d <<= 1) { s += __shfl_xor(s, d, 64); q += __shfl_xor(q, d, 64); }
    __shared__ float red[8];
    int l = tid & 63, w = tid >> 6;
    if (l == 0) { red[w] = s; red[4 + w] = q; }
    __syncthreads();
    s = red[0] + red[1] + red[2] + red[3];
    q = red[4] + red[5] + red[6] + red[7];
    float mu = s * (1.f / 1024.f);
    float var = q * (1.f / 1024.f) - mu * mu;
    float rstd = rsqrtf(var + 1e-5f);
    float4 g4 = *(const float4*)(gamma + tid * 4);
    float4 b4 = *(const float4*)(beta + tid * 4);
    u16x4 ob;
    ob[0] = f2bf((v0 - mu) * rstd * g4.x + b4.x);
    ob[1] = f2bf((v1 - mu) * rstd * g4.y + b4.y);
    ob[2] = f2bf((v2 - mu) * rstd * g4.z + b4.z);
    ob[3] = f2bf((v3 - mu) * rstd * g4.w + b4.w);
    *(u16x4*)(outb + (size_t)row * 1024 + tid * 4) = ob;
}

// ---------- LayerNorm, bf16 in -> f32 out (row = 1024) ----------
__global__ __launch_bounds__(256) void k_ln_bf(const unsigned short* __restrict__ in,
                                               const float* __restrict__ gamma,
                                               const float* __restrict__ beta,
                                               float* __restrict__ outf) {
    int row = blockIdx.x, tid = threadIdx.x;
    u16x4 raw = *(const u16x4*)(in + (size_t)row * 1024 + tid * 4);
    float v0 = bf2f(raw[0]), v1 = bf2f(raw[1]), v2 = bf2f(raw[2]), v3 = bf2f(raw[3]);
    float s = v0 + v1 + v2 + v3;
    float q = v0 * v0 + v1 * v1 + v2 * v2 + v3 * v3;
#pragma unroll
    for (int d = 1; d < 64; d <<= 1) { s += __shfl_xor(s, d, 64); q += __shfl_xor(q, d, 64); }
    __shared__ float red[8];
    int l = tid & 63, w = tid >> 6;
    if (l == 0) { red[w] = s; red[4 + w] = q; }
    __syncthreads();
    s = red[0] + red[1] + red[2] + red[3];
    q = red[4] + red[5] + red[6] + red[7];
    float mu = s * (1.f / 1024.f);
    float var = q * (1.f / 1024.f) - mu * mu;
    float rstd = rsqrtf(var + 1e-5f);
    float4 g4 = *(const float4*)(gamma + tid * 4);
    float4 b4 = *(const float4*)(beta + tid * 4);
    float4 y;
    y.x = (v0 - mu) * rstd * g4.x + b4.x;
    y.y = (v1 - mu) * rstd * g4.y + b4.y;
    y.z = (v2 - mu) * rstd * g4.z + b4.z;
    y.w = (v3 - mu) * rstd * g4.w + b4.w;
    *(float4*)(outf + (size_t)row * 1024 + tid * 4) = y;
}

// ---------- host launch ----------
extern "C" void kernel_launch(void* const* d_in, const int* in_sizes, int n_in,
                              void* d_out, int out_size, void* d_ws, size_t ws_size,
                              hipStream_t stream) {
    const float* x    = (const float*)d_in[0];
    const float* w_q  = (const float*)d_in[1];
    const float* b_q  = (const float*)d_in[2];
    const float* a_q  = (const float*)d_in[3];
    const float* bb_q = (const float*)d_in[4];
    const float* w_k  = (const float*)d_in[5];
    const float* b_k  = (const float*)d_in[6];
    const float* a_k  = (const float*)d_in[7];
    const float* bb_k = (const float*)d_in[8];
    const float* w_v  = (const float*)d_in[9];
    const float* b_v  = (const float*)d_in[10];
    const float* a_v  = (const float*)d_in[11];
    const float* bb_v = (const float*)d_in[12];
    const float* w_o  = (const float*)d_in[13];
    const float* b_o  = (const float*)d_in[14];
    const float* a_o  = (const float*)d_in[15];
    const float* bb_o = (const float*)d_in[16];
    const float* nw1  = (const float*)d_in[17];
    const float* nb1  = (const float*)d_in[18];
    const float* w_up = (const float*)d_in[19];
    const float* b_up = (const float*)d_in[20];
    const float* a_up = (const float*)d_in[21];
    const float* bb_up= (const float*)d_in[22];
    const float* w_dn = (const float*)d_in[23];
    const float* b_dn = (const float*)d_in[24];
    const float* a_dn = (const float*)d_in[25];
    const float* bb_dn= (const float*)d_in[26];
    const float* nw2  = (const float*)d_in[27];
    const float* nb2  = (const float*)d_in[28];
    const float* mask = (const float*)d_in[29];
    float* out = (float*)d_out;

    char* W = (char*)d_ws;
    size_t off = 0;
    auto alloc = [&](size_t bytes) { size_t r = off; off += (bytes + 1023) & ~(size_t)1023; return r; };

    unsigned short* WT_QKV = (unsigned short*)(W + alloc(3072ull * 1024 * 2));
    unsigned short* WT_O   = (unsigned short*)(W + alloc(1024ull * 1024 * 2));
    unsigned short* WT_UP  = (unsigned short*)(W + alloc(4096ull * 1024 * 2));
    unsigned short* WT_DN  = (unsigned short*)(W + alloc(1024ull * 4096 * 2));
    float* BIAS_QKV        = (float*)(W + alloc(3072ull * 4));
    unsigned short* XBF    = (unsigned short*)(W + alloc(8192ull * 1024 * 2)); // x bf16, later xm bf16
    unsigned short* BIG    = (unsigned short*)(W + alloc(8192ull * 4096 * 2)); // qkv, later fn
    unsigned short* O_BF   = (unsigned short*)(W + alloc(8192ull * 1024 * 2));
    unsigned short* OFB    = (unsigned short*)(W + alloc(8192ull * 1024 * 2)); // o_final bf16
    unsigned short* DNB    = (unsigned short*)(W + alloc(8192ull * 1024 * 2)); // down-out bf16
    (void)ws_size; (void)in_sizes; (void)n_in; (void)out_size;

    unsigned short* QKV = BIG;                 // [8192][3072]
    unsigned short* FN  = BIG;                 // [8192][4096]
    unsigned short* XMB = XBF;                 // x_medium bf16 (reuse)

    // 1) fused prep: x->bf16, 6 LoRA-folded weight transposes, bias concat (one launch)
    {
        PrepArgs pa{};
        int base = 0, i = 0;
        auto add = [&](const float* src, const float* a, const float* bb,
                       unsigned short* dst, int R, int C, int ds, int type) {
            int cnt;
            if (type == 0) cnt = (R * C) / (256 * 8);
            else if (type == 3) cnt = ((C + 31) / 32) * ((R + 31) / 32);
            else cnt = 12;
            pa.d[i] = {src, a, bb, dst, R, C, ds, (type == 3) ? (C + 31) / 32 : 1, base, type};
            base += cnt; i++;
        };
        add(x, nullptr, nullptr, XBF, 8192, 1024, 0, 0);
        add(w_q, a_q, bb_q, WT_QKV, 1024, 1024, 1024, 3);
        add(w_k, a_k, bb_k, WT_QKV + 1024ull * 1024, 1024, 1024, 1024, 3);
        add(w_v, a_v, bb_v, WT_QKV + 2048ull * 1024, 1024, 1024, 1024, 3);
        add(w_o, a_o, bb_o, WT_O, 1024, 1024, 1024, 3);
        add(w_up, a_up, bb_up, WT_UP, 1024, 4096, 1024, 3);
        add(w_dn, a_dn, bb_dn, WT_DN, 4096, 1024, 4096, 3);
        add(nullptr, nullptr, nullptr, nullptr, 0, 0, 0, 2);  // bias concat
        pa.nd = i;
        pa.bq = b_q; pa.bk = b_k; pa.bv = b_v; pa.bias_out = BIAS_QKV;
        k_prep<<<dim3(base), dim3(256), 0, stream>>>(pa);
    }
    // 2) QKV GEMM (gridDim.x=24 > 8 -> natural)
    {
        GemmArgs ga{XBF, WT_QKV, BIAS_QKV, nullptr, nullptr, nullptr, QKV,
                    8192, 3072, 1024, 0};
        k_gemm<0, false, true><<<dim3(24, 64), dim3(256), 0, stream>>>(ga);
    }
    // 3) attention
    k_attn<<<dim3(8, 256), dim3(256), 0, stream>>>(QKV, mask, O_BF);
    // 4) o_final(bf16) = o@W_O' + b_o + x  (gridDim.x=8 -> chunk swizzle)
    {
        GemmArgs ga{O_BF, WT_O, b_o, x, nullptr, nullptr, OFB,
                    8192, 1024, 1024, 1};
        k_gemm<1, false, true><<<dim3(8, 64), dim3(256), 0, stream>>>(ga);
    }
    // 5) LN1: bf16 in -> XMB bf16
    k_ln_b<<<dim3(8192), dim3(256), 0, stream>>>(OFB, nw1, nb1, XMB);
    // 6) up path (gridDim.x=32 > 8 -> natural)
    {
        GemmArgs ga{XMB, WT_UP, b_up, nullptr, nullptr, nullptr, FN,
                    8192, 4096, 1024, 0};
        k_gemm<0, true, true><<<dim3(32, 64), dim3(256), 0, stream>>>(ga);
    }
    // 7) down path (gridDim.x=8 -> chunk swizzle); residual = XMB bf16; output DNB bf16
    {
        GemmArgs ga{FN, WT_DN, b_dn, nullptr, XMB, nullptr, DNB,
                    8192, 1024, 4096, 1};
        k_gemm<2, false, true><<<dim3(8, 64), dim3(256), 0, stream>>>(ga);
    }
    // 8) LN2: bf16 in -> out (f32)
    k_ln_bf<<<dim3(8192), dim3(256), 0, stream>>>(DNB, nw2, nb2, out);
}

// Round 14
// 409.435 us; speedup vs baseline: 1.5850x; 1.5850x over previous
//
#include <hip/hip_runtime.h>
#include <stdint.h>

// ---------- types ----------
typedef __attribute__((ext_vector_type(8))) short bf16x8;
typedef __attribute__((ext_vector_type(4))) float f32x4;
typedef __attribute__((ext_vector_type(8))) unsigned short u16x8;
typedef __attribute__((ext_vector_type(4))) unsigned short u16x4;
typedef __attribute__((address_space(3))) uint32_t as3_u32;
typedef const __attribute__((address_space(1))) uint32_t as1_u32;

#define DEV __device__ __forceinline__

DEV float bf2f(unsigned short u) {
    union { unsigned int i; float f; } x; x.i = ((unsigned int)u) << 16; return x.f;
}
DEV unsigned short f2bf(float f) {
    union { float f; unsigned int i; } x; x.f = f;
    unsigned int i = x.i;
    return (unsigned short)((i + 0x7FFFu + ((i >> 16) & 1u)) >> 16);  // RNE, no NaN in data
}

// ---------- fused prep: x->bf16 convert, LoRA-folded weight transposes, bias concat ----------
// type 0: flat f32->bf16 convert
// type 2: qkv bias concat
// type 3: fold-transpose  dst[c][r] = bf16( src[r][c] + sum_j a[r][j]*bb[j][c] )
struct PrepDesc {
    const float* src; const float* a; const float* bb; unsigned short* dst;
    int R, C, ds, gx, base, type;
};
struct PrepArgs {
    PrepDesc d[10]; int nd;
    const float* bq; const float* bk; const float* bv; float* bias_out;
};

__global__ __launch_bounds__(256) void k_prep(PrepArgs A) {
    __shared__ float t[32][33];
    __shared__ float aL[32][17];
    __shared__ float bbL[16][33];
    int b = blockIdx.x, tid = threadIdx.x;
    int i = 0;
    while (i + 1 < A.nd && A.d[i + 1].base <= b) i++;
    PrepDesc d = A.d[i];
    int local = b - d.base;
    if (d.type == 0) {
        size_t idx = (size_t)local * 256 + tid;
        const float4* p = (const float4*)(d.src + idx * 8);
        float4 a = p[0], c = p[1];
        u16x8 o;
        o[0] = f2bf(a.x); o[1] = f2bf(a.y); o[2] = f2bf(a.z); o[3] = f2bf(a.w);
        o[4] = f2bf(c.x); o[5] = f2bf(c.y); o[6] = f2bf(c.z); o[7] = f2bf(c.w);
        *(u16x8*)(d.dst + idx * 8) = o;
    } else if (d.type == 3) {
        int bx = local % d.gx, by = local / d.gx;
        int c0 = bx * 32, r0 = by * 32;
        int tx = tid & 31, ty = tid >> 5;
#pragma unroll
        for (int k = 0; k < 4; k++) {
            int r = r0 + ty + k * 8, c = c0 + tx;
            t[ty + k * 8][tx] = (r < d.R && c < d.C) ? d.src[(size_t)r * d.C + c] : 0.f;
        }
        {
            int idx = tid * 2;
            int i0 = idx >> 4, j0 = idx & 15;
            aL[i0][j0] = (r0 + i0 < d.R) ? d.a[(size_t)(r0 + i0) * 16 + j0] : 0.f;
            int idx1 = idx + 1;
            int i1 = idx1 >> 4, j1 = idx1 & 15;
            aL[i1][j1] = (r0 + i1 < d.R) ? d.a[(size_t)(r0 + i1) * 16 + j1] : 0.f;
        }
        {
            int idx = tid * 2;
            int j0 = idx >> 5, i0 = idx & 31;
            bbL[j0][i0] = (c0 + i0 < d.C) ? d.bb[(size_t)j0 * d.C + c0 + i0] : 0.f;
            int idx1 = idx + 1;
            int j1 = idx1 >> 5, i1 = idx1 & 31;
            bbL[j1][i1] = (c0 + i1 < d.C) ? d.bb[(size_t)j1 * d.C + c0 + i1] : 0.f;
        }
        __syncthreads();
#pragma unroll
        for (int k = 0; k < 4; k++) {
            int c = c0 + ty + k * 8, r = r0 + tx;
            if (c < d.C && r < d.R) {
                float acc = t[tx][ty + k * 8];
#pragma unroll
                for (int j = 0; j < 16; j++) acc += aL[tx][j] * bbL[j][ty + k * 8];
                d.dst[(size_t)c * d.ds + r] = f2bf(acc);
            }
        }
    } else {
        int idx = local * 256 + tid;
        if (idx < 3072)
            A.bias_out[idx] = (idx < 1024) ? A.bq[idx]
                            : (idx < 2048) ? A.bk[idx - 1024] : A.bv[idx - 2048];
    }
}

// ---------- main GEMM (m97-style SINGLE-buffered, 128x128, 4 waves, 4 blocks/CU):
// C = A@B'^T + bias (+res)(gelu?)   [LoRA pre-folded into B']
// r13 lesson: (256,5) = 5 waves/SIMD -> ~100-reg budget -> acc spills to scratch (223us).
// (256,4) = 4 waves/SIMD = 128 regs/wave: VGPR 64 + AGPR 64 fits exactly, zero spill.
// Keep r13's conflict-free chunk-XOR [128][128] epilogue (bank conflicts 262K -> 0).
// XCD swizzle SHAPE-CONDITIONAL (r6): swz=1 (chunk-by-m) only when gridDim.x <= 8.
struct GemmArgs {
    const unsigned short* A;    // [M][K] bf16
    const unsigned short* B;    // [N][K] bf16 (pre-transposed, LoRA-folded weight)
    const float* bias;          // [N]
    const float* res;           // [M][N] f32 (RES==1)
    const unsigned short* resb; // [M][N] bf16 (RES==2)
    float* outf;                // OUTB==false
    unsigned short* outb;       // OUTB==true
    int M, N, K, swz;
};

template <int RES, bool GELU, bool OUTB>
__global__ __launch_bounds__(256, 4) void k_gemm(GemmArgs P) {
    __shared__ __align__(128) unsigned short smem[16384];  // 32768 B: main A|B; epilogue 128x128 swz
    int tid = threadIdx.x, l = tid & 63, w = tid >> 6;
    int wm = w >> 1, wn = w & 1, lr = l & 15, g = l >> 4, h3 = l & 7;

    // ---- block mapping ----
    int n0, m0;
    if (P.swz) {
        int nwg = gridDim.x * gridDim.y;
        int lin = blockIdx.y * gridDim.x + blockIdx.x;
        int wg = (lin & 7) * (nwg >> 3) + (lin >> 3);
        n0 = (wg % gridDim.x) * 128; m0 = (wg / gridDim.x) * 128;
    } else {
        n0 = blockIdx.x * 128; m0 = blockIdx.y * 128;
    }

    // per-lane staging sources (pre-swizzled global chunk: LDS slot (r,p) holds chunk c = p^(r&7))
    const unsigned short* pa[4];
    const unsigned short* pb[4];
#pragma unroll
    for (int i = 0; i < 4; i++) {
        int idx = i * 256 + w * 64 + l;
        int r = idx >> 3, p = idx & 7, cc = p ^ (r & 7);
        pa[i] = P.A + (size_t)(m0 + r) * P.K + cc * 8;
        pb[i] = P.B + (size_t)(n0 + r) * P.K + cc * 8;
    }
    f32x4 acc[4][4];
#pragma unroll
    for (int a = 0; a < 4; a++)
#pragma unroll
        for (int b = 0; b < 4; b++) acc[a][b] = (f32x4){0.f, 0.f, 0.f, 0.f};

    int KT = P.K >> 6;
    for (int kt = 0; kt < KT; kt++) {
#pragma unroll
        for (int i = 0; i < 4; i++) {
            unsigned int base = i * 2048 + w * 512;  // ushort elems, uniform per wave
            __builtin_amdgcn_global_load_lds((as1_u32*)(pa[i] + kt * 64),
                                             (as3_u32*)(smem + base), 16, 0, 0);
            __builtin_amdgcn_global_load_lds((as1_u32*)(pb[i] + kt * 64),
                                             (as3_u32*)(smem + base + 8192), 16, 0, 0);
        }
        __syncthreads();
        const unsigned short* bufA = smem;
        const unsigned short* bufB = smem + 8192;
#pragma unroll
        for (int ks = 0; ks < 2; ks++) {
            bf16x8 af[4], bfr[4];
#pragma unroll
            for (int mi = 0; mi < 4; mi++) {
                int row = wm * 64 + mi * 16 + lr;
                af[mi] = *(const bf16x8*)(bufA + row * 64 + (((ks * 4 + g) ^ h3) * 8));
            }
#pragma unroll
            for (int ni = 0; ni < 4; ni++) {
                int row = wn * 64 + ni * 16 + lr;
                bfr[ni] = *(const bf16x8*)(bufB + row * 64 + (((ks * 4 + g) ^ h3) * 8));
            }
#pragma unroll
            for (int mi = 0; mi < 4; mi++)
#pragma unroll
                for (int ni = 0; ni < 4; ni++)
                    acc[mi][ni] = __builtin_amdgcn_mfma_f32_16x16x32_bf16(af[mi], bfr[ni],
                                                                          acc[mi][ni], 0, 0, 0);
        }
        __syncthreads();
    }

    if constexpr (OUTB) {
        // ---- bf16 output: bias (+res) (+gelu), chunk-XOR swizzled LDS bounce, coalesced out ----
        unsigned short* eb = smem;   // [128][128] bf16, chunk p of row m at p^(m&7)
#pragma unroll
        for (int ni = 0; ni < 4; ni++) {
            int nn = wn * 64 + ni * 16 + lr;
            float bv = P.bias[n0 + nn];
#pragma unroll
            for (int mi = 0; mi < 4; mi++) {
#pragma unroll
                for (int r = 0; r < 4; r++) {
                    int mm = wm * 64 + mi * 16 + g * 4 + r;
                    float v = acc[mi][ni][r] + bv;
                    if constexpr (RES == 1) v += P.res[(size_t)(m0 + mm) * P.N + n0 + nn];
                    if constexpr (RES == 2) v += bf2f(P.resb[(size_t)(m0 + mm) * P.N + n0 + nn]);
                    if constexpr (GELU) {
                        float u = 0.7978845608f * v * (1.f + 0.044715f * v * v);
                        float e = __expf(2.f * u);
                        v = v - v / (e + 1.f);
                    }
                    eb[mm * 128 + (((nn >> 3) ^ (mm & 7)) * 8) + (nn & 7)] = f2bf(v);
                }
            }
        }
        __syncthreads();
#pragma unroll
        for (int i = 0; i < 8; i++) {
            int idx = i * 256 + tid;
            int row = idx >> 4, c = idx & 15;
            u16x8 d = *(const u16x8*)(eb + row * 128 + ((c ^ (row & 7)) * 8));
            *(u16x8*)(P.outb + (size_t)(m0 + row) * P.N + n0 + c * 8) = d;
        }
    } else {
        // ---- f32 output (+res): direct stores ----
#pragma unroll
        for (int ni = 0; ni < 4; ni++) {
            int n = n0 + wn * 64 + ni * 16 + lr;
            float bv = P.bias[n];
#pragma unroll
            for (int mi = 0; mi < 4; mi++) {
#pragma unroll
                for (int r = 0; r < 4; r++) {
                    int m = m0 + wm * 64 + mi * 16 + g * 4 + r;
                    float v = acc[mi][ni][r] + bv;
                    if constexpr (RES == 1) v += P.res[(size_t)m * P.N + n];
                    if constexpr (RES == 2) v += bf2f(P.resb[(size_t)m * P.N + n]);
                    P.outf[(size_t)m * P.N + n] = v;
                }
            }
        }
    }
}

// ---------- flash attention: qkv [8192][3072] bf16 -> o [8192][1024] bf16 ----------
__global__ __launch_bounds__(256) void k_attn(const unsigned short* __restrict__ qkv,
                                              const float* __restrict__ mask,
                                              unsigned short* __restrict__ o) {
    __shared__ __align__(128) unsigned short Kl[64 * 64];
    __shared__ __align__(128) unsigned short Vt[64 * 64];
    __shared__ __align__(128) unsigned short Pl[4 * 16 * 64];
    int tid = threadIdx.x, l = tid & 63, w = tid >> 6;
    int b = blockIdx.y >> 4, h = blockIdx.y & 15;
    int qbase = blockIdx.x * 64;
    int lr = l & 15, g = l >> 4, h3 = l & 7;

    size_t rowQ = (size_t)(b * 512 + qbase + w * 16 + lr) * 3072 + h * 64;
    bf16x8 qf0 = *(const bf16x8*)(qkv + rowQ + g * 8);
    bf16x8 qf1 = *(const bf16x8*)(qkv + rowQ + 32 + g * 8);

    f32x4 oacc[4];
    float mrun[4], lrun[4];
#pragma unroll
    for (int i = 0; i < 4; i++) { oacc[i] = (f32x4){0.f, 0.f, 0.f, 0.f}; mrun[i] = -1e30f; lrun[i] = 0.f; }

    int sr = tid >> 3, sc = tid & 7;          // K staging
    int cV = tid & 7, kv0 = (tid >> 3) * 2;   // V staging (pairs)
    const unsigned short* kbase = qkv + (size_t)(b * 512) * 3072 + 1024 + h * 64;
    const unsigned short* vbase = qkv + (size_t)(b * 512) * 3072 + 2048 + h * 64;
    unsigned short* pw = Pl + w * 1024;

    for (int kt = 0; kt < 8; kt++) {
#pragma unroll
        for (int i = 0; i < 2; i++) {
            int r = sr + i * 32;
            u16x8 kd = *(const u16x8*)(kbase + (size_t)(kt * 64 + r) * 3072 + sc * 8);
            *(u16x8*)(Kl + r * 64 + ((sc ^ (r & 7)) * 8)) = kd;
        }
        {
            u16x8 v0 = *(const u16x8*)(vbase + (size_t)(kt * 64 + kv0) * 3072 + cV * 8);
            u16x8 v1 = *(const u16x8*)(vbase + (size_t)(kt * 64 + kv0 + 1) * 3072 + cV * 8);
            int kc = kv0 >> 3, ke = kv0 & 7;
#pragma unroll
            for (int j = 0; j < 8; j++) {
                int hd = cV * 8 + j;
                unsigned int pr = (unsigned int)v0[j] | ((unsigned int)v1[j] << 16);
                *(unsigned int*)(Vt + hd * 64 + ((kc ^ (hd & 7)) * 8) + ke) = pr;
            }
        }
        __syncthreads();

        f32x4 s[4];
#pragma unroll
        for (int i = 0; i < 4; i++) s[i] = (f32x4){0.f, 0.f, 0.f, 0.f};
#pragma unroll
        for (int ks = 0; ks < 2; ks++) {
            bf16x8 qa = ks ? qf1 : qf0;
#pragma unroll
            for (int nf = 0; nf < 4; nf++) {
                int kr = lr + nf * 16;
                bf16x8 kf = *(const bf16x8*)(Kl + kr * 64 + (((ks * 4 + g) ^ h3) * 8));
                s[nf] = __builtin_amdgcn_mfma_f32_16x16x32_bf16(qa, kf, s[nf], 0, 0, 0);
            }
        }
        const float* mrow = mask + b * 512 + kt * 64;
#pragma unroll
        for (int nf = 0; nf < 4; nf++) {
            float mk = mrow[lr + nf * 16];
            s[nf] = s[nf] * 0.125f + mk;
        }
        float mx[4];
#pragma unroll
        for (int r = 0; r < 4; r++) {
            mx[r] = fmaxf(fmaxf(s[0][r], s[1][r]), fmaxf(s[2][r], s[3][r]));
#pragma unroll
            for (int d = 1; d < 16; d <<= 1) mx[r] = fmaxf(mx[r], __shfl_xor(mx[r], d, 64));
        }
        float al[4];
#pragma unroll
        for (int r = 0; r < 4; r++) {
            float mn = fmaxf(mrun[r], mx[r]);
            al[r] = __expf(mrun[r] - mn);
            mrun[r] = mn;
        }
        float rs[4] = {0.f, 0.f, 0.f, 0.f};
#pragma unroll
        for (int nf = 0; nf < 4; nf++)
#pragma unroll
            for (int r = 0; r < 4; r++) {
                float p = __expf(s[nf][r] - mrun[r]);
                s[nf][r] = p;
                rs[r] += p;
            }
#pragma unroll
        for (int r = 0; r < 4; r++) {
#pragma unroll
            for (int d = 1; d < 16; d <<= 1) rs[r] += __shfl_xor(rs[r], d, 64);
            lrun[r] = lrun[r] * al[r] + rs[r];
        }
#pragma unroll
        for (int nh = 0; nh < 4; nh++) {
            f32x4 t = oacc[nh];
            t[0] *= al[0]; t[1] *= al[1]; t[2] *= al[2]; t[3] *= al[3];
            oacc[nh] = t;
        }
#pragma unroll
        for (int nf = 0; nf < 4; nf++) {
            int pc = lr + nf * 16;
#pragma unroll
            for (int r = 0; r < 4; r++) {
                int prr = g * 4 + r;
                pw[prr * 64 + (((pc >> 3) ^ (prr & 7)) * 8) + (pc & 7)] = f2bf(s[nf][r]);
            }
        }
#pragma unroll
        for (int ks = 0; ks < 2; ks++) {
            bf16x8 pa = *(const bf16x8*)(pw + lr * 64 + (((ks * 4 + g) ^ h3) * 8));
#pragma unroll
            for (int nh = 0; nh < 4; nh++) {
                int vr = lr + nh * 16;
                bf16x8 vf = *(const bf16x8*)(Vt + vr * 64 + (((ks * 4 + g) ^ h3) * 8));
                oacc[nh] = __builtin_amdgcn_mfma_f32_16x16x32_bf16(pa, vf, oacc[nh], 0, 0, 0);
            }
        }
        __syncthreads();
    }
#pragma unroll
    for (int r = 0; r < 4; r++) {
        float inv = 1.f / lrun[r];
        size_t orow = (size_t)(b * 512 + qbase + w * 16 + g * 4 + r) * 1024 + h * 64;
#pragma unroll
        for (int nh = 0; nh < 4; nh++)
            o[orow + lr + nh * 16] = f2bf(oacc[nh][r] * inv);
    }
}

// ---------- LayerNorm, bf16 in -> bf16 out (row = 1024) ----------
__global__ __launch_bounds__(256) void k_ln_b(const unsigned short* __restrict__ in,
                                              const float* __restrict__ gamma,
                                              const float* __restrict__ beta,
                                              unsigned short* __restrict__ outb) {
    int row = blockIdx.x, tid = threadIdx.x;
    u16x4 raw = *(const u16x4*)(in + (size_t)row * 1024 + tid * 4);
    float v0 = bf2f(raw[0]), v1 = bf2f(raw[1]), v2 = bf2f(raw[2]), v3 = bf2f(raw[3]);
    float s = v0 + v1 + v2 + v3;
    float q = v0 * v0 + v1 * v1 + v2 * v2 + v3 * v3;
#pragma unroll
    for (int d = 1; d < 64; d <<= 1) { s += __shfl_xor(s, d, 64); q += __shfl_xor(q, d, 64); }
    __shared__ float red[8];
    int l = tid & 63, w = tid >> 6;
    if (l == 0) { red[w] = s; red[4 + w] = q; }
    __syncthreads();
    s = red[0] + red[1] + red[2] + red[3];
    q = red[4] + red[5] + red[6] + red[7];
    float mu = s * (1.f / 1024.f);
    float var = q * (1.f / 1024.f) - mu * mu;
    float rstd = rsqrtf(var + 1e-5f);
    float4 g4 = *(const float4*)(gamma + tid * 4);
    float4 b4 = *(const float4*)(beta + tid * 4);
    u16x4 ob;
    ob[0] = f2bf((v0 - mu) * rstd * g4.x + b4.x);
    ob[1] = f2bf((v1 - mu) * rstd * g4.y + b4.y);
    ob[2] = f2bf((v2 - mu) * rstd * g4.z + b4.z);
    ob[3] = f2bf((v3 - mu) * rstd * g4.w + b4.w);
    *(u16x4*)(outb + (size_t)row * 1024 + tid * 4) = ob;
}

// ---------- LayerNorm, bf16 in -> f32 out (row = 1024) ----------
__global__ __launch_bounds__(256) void k_ln_bf(const unsigned short* __restrict__ in,
                                               const float* __restrict__ gamma,
                                               const float* __restrict__ beta,
                                               float* __restrict__ outf) {
    int row = blockIdx.x, tid = threadIdx.x;
    u16x4 raw = *(const u16x4*)(in + (size_t)row * 1024 + tid * 4);
    float v0 = bf2f(raw[0]), v1 = bf2f(raw[1]), v2 = bf2f(raw[2]), v3 = bf2f(raw[3]);
    float s = v0 + v1 + v2 + v3;
    float q = v0 * v0 + v1 * v1 + v2 * v2 + v3 * v3;
#pragma unroll
    for (int d = 1; d < 64; d <<= 1) { s += __shfl_xor(s, d, 64); q += __shfl_xor(q, d, 64); }
    __shared__ float red[8];
    int l = tid & 63, w = tid >> 6;
    if (l == 0) { red[w] = s; red[4 + w] = q; }
    __syncthreads();
    s = red[0] + red[1] + red[2] + red[3];
    q = red[4] + red[5] + red[6] + red[7];
    float mu = s * (1.f / 1024.f);
    float var = q * (1.f / 1024.f) - mu * mu;
    float rstd = rsqrtf(var + 1e-5f);
    float4 g4 = *(const float4*)(gamma + tid * 4);
    float4 b4 = *(const float4*)(beta + tid * 4);
    float4 y;
    y.x = (v0 - mu) * rstd * g4.x + b4.x;
    y.y = (v1 - mu) * rstd * g4.y + b4.y;
    y.z = (v2 - mu) * rstd * g4.z + b4.z;
    y.w = (v3 - mu) * rstd * g4.w + b4.w;
    *(float4*)(outf + (size_t)row * 1024 + tid * 4) = y;
}

// ---------- host launch ----------
extern "C" void kernel_launch(void* const* d_in, const int* in_sizes, int n_in,
                              void* d_out, int out_size, void* d_ws, size_t ws_size,
                              hipStream_t stream) {
    const float* x    = (const float*)d_in[0];
    const float* w_q  = (const float*)d_in[1];
    const float* b_q  = (const float*)d_in[2];
    const float* a_q  = (const float*)d_in[3];
    const float* bb_q = (const float*)d_in[4];
    const float* w_k  = (const float*)d_in[5];
    const float* b_k  = (const float*)d_in[6];
    const float* a_k  = (const float*)d_in[7];
    const float* bb_k = (const float*)d_in[8];
    const float* w_v  = (const float*)d_in[9];
    const float* b_v  = (const float*)d_in[10];
    const float* a_v  = (const float*)d_in[11];
    const float* bb_v = (const float*)d_in[12];
    const float* w_o  = (const float*)d_in[13];
    const float* b_o  = (const float*)d_in[14];
    const float* a_o  = (const float*)d_in[15];
    const float* bb_o = (const float*)d_in[16];
    const float* nw1  = (const float*)d_in[17];
    const float* nb1  = (const float*)d_in[18];
    const float* w_up = (const float*)d_in[19];
    const float* b_up = (const float*)d_in[20];
    const float* a_up = (const float*)d_in[21];
    const float* bb_up= (const float*)d_in[22];
    const float* w_dn = (const float*)d_in[23];
    const float* b_dn = (const float*)d_in[24];
    const float* a_dn = (const float*)d_in[25];
    const float* bb_dn= (const float*)d_in[26];
    const float* nw2  = (const float*)d_in[27];
    const float* nb2  = (const float*)d_in[28];
    const float* mask = (const float*)d_in[29];
    float* out = (float*)d_out;

    char* W = (char*)d_ws;
    size_t off = 0;
    auto alloc = [&](size_t bytes) { size_t r = off; off += (bytes + 1023) & ~(size_t)1023; return r; };

    unsigned short* WT_QKV = (unsigned short*)(W + alloc(3072ull * 1024 * 2));
    unsigned short* WT_O   = (unsigned short*)(W + alloc(1024ull * 1024 * 2));
    unsigned short* WT_UP  = (unsigned short*)(W + alloc(4096ull * 1024 * 2));
    unsigned short* WT_DN  = (unsigned short*)(W + alloc(1024ull * 4096 * 2));
    float* BIAS_QKV        = (float*)(W + alloc(3072ull * 4));
    unsigned short* XBF    = (unsigned short*)(W + alloc(8192ull * 1024 * 2)); // x bf16, later xm bf16
    unsigned short* BIG    = (unsigned short*)(W + alloc(8192ull * 4096 * 2)); // qkv, later fn
    unsigned short* O_BF   = (unsigned short*)(W + alloc(8192ull * 1024 * 2));
    unsigned short* OFB    = (unsigned short*)(W + alloc(8192ull * 1024 * 2)); // o_final bf16
    unsigned short* DNB    = (unsigned short*)(W + alloc(8192ull * 1024 * 2)); // down-out bf16
    (void)ws_size; (void)in_sizes; (void)n_in; (void)out_size;

    unsigned short* QKV = BIG;                 // [8192][3072]
    unsigned short* FN  = BIG;                 // [8192][4096]
    unsigned short* XMB = XBF;                 // x_medium bf16 (reuse)

    // 1) fused prep: x->bf16, 6 LoRA-folded weight transposes, bias concat (one launch)
    {
        PrepArgs pa{};
        int base = 0, i = 0;
        auto add = [&](const float* src, const float* a, const float* bb,
                       unsigned short* dst, int R, int C, int ds, int type) {
            int cnt;
            if (type == 0) cnt = (R * C) / (256 * 8);
            else if (type == 3) cnt = ((C + 31) / 32) * ((R + 31) / 32);
            else cnt = 12;
            pa.d[i] = {src, a, bb, dst, R, C, ds, (type == 3) ? (C + 31) / 32 : 1, base, type};
            base += cnt; i++;
        };
        add(x, nullptr, nullptr, XBF, 8192, 1024, 0, 0);
        add(w_q, a_q, bb_q, WT_QKV, 1024, 1024, 1024, 3);
        add(w_k, a_k, bb_k, WT_QKV + 1024ull * 1024, 1024, 1024, 1024, 3);
        add(w_v, a_v, bb_v, WT_QKV + 2048ull * 1024, 1024, 1024, 1024, 3);
        add(w_o, a_o, bb_o, WT_O, 1024, 1024, 1024, 3);
        add(w_up, a_up, bb_up, WT_UP, 1024, 4096, 1024, 3);
        add(w_dn, a_dn, bb_dn, WT_DN, 4096, 1024, 4096, 3);
        add(nullptr, nullptr, nullptr, nullptr, 0, 0, 0, 2);  // bias concat
        pa.nd = i;
        pa.bq = b_q; pa.bk = b_k; pa.bv = b_v; pa.bias_out = BIAS_QKV;
        k_prep<<<dim3(base), dim3(256), 0, stream>>>(pa);
    }
    // 2) QKV GEMM (gridDim.x=24 > 8 -> natural)
    {
        GemmArgs ga{XBF, WT_QKV, BIAS_QKV, nullptr, nullptr, nullptr, QKV,
                    8192, 3072, 1024, 0};
        k_gemm<0, false, true><<<dim3(24, 64), dim3(256), 0, stream>>>(ga);
    }
    // 3) attention
    k_attn<<<dim3(8, 256), dim3(256), 0, stream>>>(QKV, mask, O_BF);
    // 4) o_final(bf16) = o@W_O' + b_o + x  (gridDim.x=8 -> chunk swizzle)
    {
        GemmArgs ga{O_BF, WT_O, b_o, x, nullptr, nullptr, OFB,
                    8192, 1024, 1024, 1};
        k_gemm<1, false, true><<<dim3(8, 64), dim3(256), 0, stream>>>(ga);
    }
    // 5) LN1: bf16 in -> XMB bf16
    k_ln_b<<<dim3(8192), dim3(256), 0, stream>>>(OFB, nw1, nb1, XMB);
    // 6) up path (gridDim.x=32 > 8 -> natural)
    {
        GemmArgs ga{XMB, WT_UP, b_up, nullptr, nullptr, nullptr, FN,
                    8192, 4096, 1024, 0};
        k_gemm<0, true, true><<<dim3(32, 64), dim3(256), 0, stream>>>(ga);
    }
    // 7) down path (gridDim.x=8 -> chunk swizzle); residual = XMB bf16; output DNB bf16
    {
        GemmArgs ga{FN, WT_DN, b_dn, nullptr, XMB, nullptr, DNB,
                    8192, 1024, 4096, 1};
        k_gemm<2, false, true><<<dim3(8, 64), dim3(256), 0, stream>>>(ga);
    }
    // 8) LN2: bf16 in -> out (f32)
    k_ln_bf<<<dim3(8192), dim3(256), 0, stream>>>(DNB, nw2, nb2, out);
}

// Round 15
// 384.898 us; speedup vs baseline: 1.6860x; 1.0638x over previous
//
#include <hip/hip_runtime.h>
#include <stdint.h>

// ---------- types ----------
typedef __attribute__((ext_vector_type(8))) short bf16x8;
typedef __attribute__((ext_vector_type(4))) float f32x4;
typedef __attribute__((ext_vector_type(8))) unsigned short u16x8;
typedef __attribute__((ext_vector_type(4))) unsigned short u16x4;
typedef __attribute__((address_space(3))) uint32_t as3_u32;
typedef const __attribute__((address_space(1))) uint32_t as1_u32;

#define DEV __device__ __forceinline__

DEV float bf2f(unsigned short u) {
    union { unsigned int i; float f; } x; x.i = ((unsigned int)u) << 16; return x.f;
}
DEV unsigned short f2bf(float f) {
    union { float f; unsigned int i; } x; x.f = f;
    unsigned int i = x.i;
    return (unsigned short)((i + 0x7FFFu + ((i >> 16) & 1u)) >> 16);  // RNE, no NaN in data
}

// ---------- fused prep: x->bf16 convert, LoRA-folded weight transposes, bias concat ----------
// type 0: flat f32->bf16 convert
// type 2: qkv bias concat
// type 3: fold-transpose  dst[c][r] = bf16( src[r][c] + sum_j a[r][j]*bb[j][c] )
//         (LoRA fold: x@w + (x@a)@bb == x@(w + a@bb))
struct PrepDesc {
    const float* src; const float* a; const float* bb; unsigned short* dst;
    int R, C, ds, gx, base, type;
};
struct PrepArgs {
    PrepDesc d[10]; int nd;
    const float* bq; const float* bk; const float* bv; float* bias_out;
};

__global__ __launch_bounds__(256) void k_prep(PrepArgs A) {
    __shared__ float t[32][33];
    __shared__ float aL[32][17];
    __shared__ float bbL[16][33];
    int b = blockIdx.x, tid = threadIdx.x;
    int i = 0;
    while (i + 1 < A.nd && A.d[i + 1].base <= b) i++;
    PrepDesc d = A.d[i];
    int local = b - d.base;
    if (d.type == 0) {
        size_t idx = (size_t)local * 256 + tid;
        const float4* p = (const float4*)(d.src + idx * 8);
        float4 a = p[0], c = p[1];
        u16x8 o;
        o[0] = f2bf(a.x); o[1] = f2bf(a.y); o[2] = f2bf(a.z); o[3] = f2bf(a.w);
        o[4] = f2bf(c.x); o[5] = f2bf(c.y); o[6] = f2bf(c.z); o[7] = f2bf(c.w);
        *(u16x8*)(d.dst + idx * 8) = o;
    } else if (d.type == 3) {
        int bx = local % d.gx, by = local / d.gx;
        int c0 = bx * 32, r0 = by * 32;
        int tx = tid & 31, ty = tid >> 5;
#pragma unroll
        for (int k = 0; k < 4; k++) {
            int r = r0 + ty + k * 8, c = c0 + tx;
            t[ty + k * 8][tx] = (r < d.R && c < d.C) ? d.src[(size_t)r * d.C + c] : 0.f;
        }
        {
            int idx = tid * 2;
            int i0 = idx >> 4, j0 = idx & 15;
            aL[i0][j0] = (r0 + i0 < d.R) ? d.a[(size_t)(r0 + i0) * 16 + j0] : 0.f;
            int idx1 = idx + 1;
            int i1 = idx1 >> 4, j1 = idx1 & 15;
            aL[i1][j1] = (r0 + i1 < d.R) ? d.a[(size_t)(r0 + i1) * 16 + j1] : 0.f;
        }
        {
            int idx = tid * 2;
            int j0 = idx >> 5, i0 = idx & 31;
            bbL[j0][i0] = (c0 + i0 < d.C) ? d.bb[(size_t)j0 * d.C + c0 + i0] : 0.f;
            int idx1 = idx + 1;
            int j1 = idx1 >> 5, i1 = idx1 & 31;
            bbL[j1][i1] = (c0 + i1 < d.C) ? d.bb[(size_t)j1 * d.C + c0 + i1] : 0.f;
        }
        __syncthreads();
#pragma unroll
        for (int k = 0; k < 4; k++) {
            int c = c0 + ty + k * 8, r = r0 + tx;
            if (c < d.C && r < d.R) {
                float acc = t[tx][ty + k * 8];
#pragma unroll
                for (int j = 0; j < 16; j++) acc += aL[tx][j] * bbL[j][ty + k * 8];
                d.dst[(size_t)c * d.ds + r] = f2bf(acc);
            }
        }
    } else {
        int idx = local * 256 + tid;
        if (idx < 3072)
            A.bias_out[idx] = (idx < 1024) ? A.bq[idx]
                            : (idx < 2048) ? A.bk[idx - 1024] : A.bv[idx - 2048];
    }
}

// ---------- main GEMM (m97-style SINGLE-buffered, 128x128, 4 waves, 4 blocks/CU):
// C = A@B'^T + bias (+res)(gelu?)   [LoRA pre-folded into B']
// r12 config (measured best, 82.5us/GEMM, occupancy 34%, MfmaUtil 36%): pad-136
// epilogue bounce, 34816 B LDS, launch_bounds(256,4). r13 (5 waves -> spill) and
// r14 (swizzled epilogue/32KB -> occupancy loss) both regressed; this is the local optimum.
// XCD swizzle SHAPE-CONDITIONAL (r6): swz=1 (chunk-by-m) only when gridDim.x <= 8.
struct GemmArgs {
    const unsigned short* A;    // [M][K] bf16
    const unsigned short* B;    // [N][K] bf16 (pre-transposed, LoRA-folded weight)
    const float* bias;          // [N]
    const float* res;           // [M][N] f32 (RES==1)
    const unsigned short* resb; // [M][N] bf16 (RES==2)
    float* outf;                // OUTB==false
    unsigned short* outb;       // OUTB==true
    int M, N, K, swz;
};

template <int RES, bool GELU, bool OUTB>
__global__ __launch_bounds__(256, 4) void k_gemm(GemmArgs P) {
    __shared__ __align__(128) unsigned short smem[17408];  // main: 16K elems; epilogue: 128x136
    int tid = threadIdx.x, l = tid & 63, w = tid >> 6;
    int wm = w >> 1, wn = w & 1, lr = l & 15, g = l >> 4, h3 = l & 7;

    // ---- block mapping ----
    int n0, m0;
    if (P.swz) {
        int nwg = gridDim.x * gridDim.y;
        int lin = blockIdx.y * gridDim.x + blockIdx.x;
        int wg = (lin & 7) * (nwg >> 3) + (lin >> 3);
        n0 = (wg % gridDim.x) * 128; m0 = (wg / gridDim.x) * 128;
    } else {
        n0 = blockIdx.x * 128; m0 = blockIdx.y * 128;
    }

    // per-lane staging sources (pre-swizzled global chunk: LDS slot (r,p) holds chunk c = p^(r&7))
    const unsigned short* pa[4];
    const unsigned short* pb[4];
#pragma unroll
    for (int i = 0; i < 4; i++) {
        int idx = i * 256 + w * 64 + l;
        int r = idx >> 3, p = idx & 7, cc = p ^ (r & 7);
        pa[i] = P.A + (size_t)(m0 + r) * P.K + cc * 8;
        pb[i] = P.B + (size_t)(n0 + r) * P.K + cc * 8;
    }
    f32x4 acc[4][4];
#pragma unroll
    for (int a = 0; a < 4; a++)
#pragma unroll
        for (int b = 0; b < 4; b++) acc[a][b] = (f32x4){0.f, 0.f, 0.f, 0.f};

    int KT = P.K >> 6;
    for (int kt = 0; kt < KT; kt++) {
#pragma unroll
        for (int i = 0; i < 4; i++) {
            unsigned int base = i * 2048 + w * 512;  // ushort elems, uniform per wave
            __builtin_amdgcn_global_load_lds((as1_u32*)(pa[i] + kt * 64),
                                             (as3_u32*)(smem + base), 16, 0, 0);
            __builtin_amdgcn_global_load_lds((as1_u32*)(pb[i] + kt * 64),
                                             (as3_u32*)(smem + base + 8192), 16, 0, 0);
        }
        __syncthreads();
        const unsigned short* bufA = smem;
        const unsigned short* bufB = smem + 8192;
#pragma unroll
        for (int ks = 0; ks < 2; ks++) {
            bf16x8 af[4], bfr[4];
#pragma unroll
            for (int mi = 0; mi < 4; mi++) {
                int row = wm * 64 + mi * 16 + lr;
                af[mi] = *(const bf16x8*)(bufA + row * 64 + (((ks * 4 + g) ^ h3) * 8));
            }
#pragma unroll
            for (int ni = 0; ni < 4; ni++) {
                int row = wn * 64 + ni * 16 + lr;
                bfr[ni] = *(const bf16x8*)(bufB + row * 64 + (((ks * 4 + g) ^ h3) * 8));
            }
#pragma unroll
            for (int mi = 0; mi < 4; mi++)
#pragma unroll
                for (int ni = 0; ni < 4; ni++)
                    acc[mi][ni] = __builtin_amdgcn_mfma_f32_16x16x32_bf16(af[mi], bfr[ni],
                                                                          acc[mi][ni], 0, 0, 0);
        }
        __syncthreads();
    }

    if constexpr (OUTB) {
        // ---- bf16 output: bias (+res) (+gelu), LDS bounce, coalesced copy-out ----
        unsigned short* eb = smem;   // [128][136] bf16 = 34.8 KB
        const int LS = 136;
#pragma unroll
        for (int ni = 0; ni < 4; ni++) {
            int nn = wn * 64 + ni * 16 + lr;
            float bv = P.bias[n0 + nn];
#pragma unroll
            for (int mi = 0; mi < 4; mi++) {
#pragma unroll
                for (int r = 0; r < 4; r++) {
                    int mm = wm * 64 + mi * 16 + g * 4 + r;
                    float v = acc[mi][ni][r] + bv;
                    if constexpr (RES == 1) v += P.res[(size_t)(m0 + mm) * P.N + n0 + nn];
                    if constexpr (RES == 2) v += bf2f(P.resb[(size_t)(m0 + mm) * P.N + n0 + nn]);
                    if constexpr (GELU) {
                        float u = 0.7978845608f * v * (1.f + 0.044715f * v * v);
                        float e = __expf(2.f * u);
                        v = v - v / (e + 1.f);
                    }
                    eb[mm * LS + nn] = f2bf(v);
                }
            }
        }
        __syncthreads();
#pragma unroll
        for (int i = 0; i < 8; i++) {
            int idx = i * 256 + tid;
            int row = idx >> 4, c = idx & 15;
            u16x8 d = *(const u16x8*)(eb + row * LS + c * 8);
            *(u16x8*)(P.outb + (size_t)(m0 + row) * P.N + n0 + c * 8) = d;
        }
    } else {
        // ---- f32 output (+res): direct stores ----
#pragma unroll
        for (int ni = 0; ni < 4; ni++) {
            int n = n0 + wn * 64 + ni * 16 + lr;
            float bv = P.bias[n];
#pragma unroll
            for (int mi = 0; mi < 4; mi++) {
#pragma unroll
                for (int r = 0; r < 4; r++) {
                    int m = m0 + wm * 64 + mi * 16 + g * 4 + r;
                    float v = acc[mi][ni][r] + bv;
                    if constexpr (RES == 1) v += P.res[(size_t)m * P.N + n];
                    if constexpr (RES == 2) v += bf2f(P.resb[(size_t)m * P.N + n]);
                    P.outf[(size_t)m * P.N + n] = v;
                }
            }
        }
    }
}

// ---------- flash attention: qkv [8192][3072] bf16 -> o [8192][1024] bf16 ----------
__global__ __launch_bounds__(256) void k_attn(const unsigned short* __restrict__ qkv,
                                              const float* __restrict__ mask,
                                              unsigned short* __restrict__ o) {
    __shared__ __align__(128) unsigned short Kl[64 * 64];
    __shared__ __align__(128) unsigned short Vt[64 * 64];
    __shared__ __align__(128) unsigned short Pl[4 * 16 * 64];
    int tid = threadIdx.x, l = tid & 63, w = tid >> 6;
    int b = blockIdx.y >> 4, h = blockIdx.y & 15;
    int qbase = blockIdx.x * 64;
    int lr = l & 15, g = l >> 4, h3 = l & 7;

    size_t rowQ = (size_t)(b * 512 + qbase + w * 16 + lr) * 3072 + h * 64;
    bf16x8 qf0 = *(const bf16x8*)(qkv + rowQ + g * 8);
    bf16x8 qf1 = *(const bf16x8*)(qkv + rowQ + 32 + g * 8);

    f32x4 oacc[4];
    float mrun[4], lrun[4];
#pragma unroll
    for (int i = 0; i < 4; i++) { oacc[i] = (f32x4){0.f, 0.f, 0.f, 0.f}; mrun[i] = -1e30f; lrun[i] = 0.f; }

    int sr = tid >> 3, sc = tid & 7;          // K staging
    int cV = tid & 7, kv0 = (tid >> 3) * 2;   // V staging (pairs)
    const unsigned short* kbase = qkv + (size_t)(b * 512) * 3072 + 1024 + h * 64;
    const unsigned short* vbase = qkv + (size_t)(b * 512) * 3072 + 2048 + h * 64;
    unsigned short* pw = Pl + w * 1024;

    for (int kt = 0; kt < 8; kt++) {
#pragma unroll
        for (int i = 0; i < 2; i++) {
            int r = sr + i * 32;
            u16x8 kd = *(const u16x8*)(kbase + (size_t)(kt * 64 + r) * 3072 + sc * 8);
            *(u16x8*)(Kl + r * 64 + ((sc ^ (r & 7)) * 8)) = kd;
        }
        {
            u16x8 v0 = *(const u16x8*)(vbase + (size_t)(kt * 64 + kv0) * 3072 + cV * 8);
            u16x8 v1 = *(const u16x8*)(vbase + (size_t)(kt * 64 + kv0 + 1) * 3072 + cV * 8);
            int kc = kv0 >> 3, ke = kv0 & 7;
#pragma unroll
            for (int j = 0; j < 8; j++) {
                int hd = cV * 8 + j;
                unsigned int pr = (unsigned int)v0[j] | ((unsigned int)v1[j] << 16);
                *(unsigned int*)(Vt + hd * 64 + ((kc ^ (hd & 7)) * 8) + ke) = pr;
            }
        }
        __syncthreads();

        f32x4 s[4];
#pragma unroll
        for (int i = 0; i < 4; i++) s[i] = (f32x4){0.f, 0.f, 0.f, 0.f};
#pragma unroll
        for (int ks = 0; ks < 2; ks++) {
            bf16x8 qa = ks ? qf1 : qf0;
#pragma unroll
            for (int nf = 0; nf < 4; nf++) {
                int kr = lr + nf * 16;
                bf16x8 kf = *(const bf16x8*)(Kl + kr * 64 + (((ks * 4 + g) ^ h3) * 8));
                s[nf] = __builtin_amdgcn_mfma_f32_16x16x32_bf16(qa, kf, s[nf], 0, 0, 0);
            }
        }
        const float* mrow = mask + b * 512 + kt * 64;
#pragma unroll
        for (int nf = 0; nf < 4; nf++) {
            float mk = mrow[lr + nf * 16];
            s[nf] = s[nf] * 0.125f + mk;
        }
        float mx[4];
#pragma unroll
        for (int r = 0; r < 4; r++) {
            mx[r] = fmaxf(fmaxf(s[0][r], s[1][r]), fmaxf(s[2][r], s[3][r]));
#pragma unroll
            for (int d = 1; d < 16; d <<= 1) mx[r] = fmaxf(mx[r], __shfl_xor(mx[r], d, 64));
        }
        float al[4];
#pragma unroll
        for (int r = 0; r < 4; r++) {
            float mn = fmaxf(mrun[r], mx[r]);
            al[r] = __expf(mrun[r] - mn);
            mrun[r] = mn;
        }
        float rs[4] = {0.f, 0.f, 0.f, 0.f};
#pragma unroll
        for (int nf = 0; nf < 4; nf++)
#pragma unroll
            for (int r = 0; r < 4; r++) {
                float p = __expf(s[nf][r] - mrun[r]);
                s[nf][r] = p;
                rs[r] += p;
            }
#pragma unroll
        for (int r = 0; r < 4; r++) {
#pragma unroll
            for (int d = 1; d < 16; d <<= 1) rs[r] += __shfl_xor(rs[r], d, 64);
            lrun[r] = lrun[r] * al[r] + rs[r];
        }
#pragma unroll
        for (int nh = 0; nh < 4; nh++) {
            f32x4 t = oacc[nh];
            t[0] *= al[0]; t[1] *= al[1]; t[2] *= al[2]; t[3] *= al[3];
            oacc[nh] = t;
        }
#pragma unroll
        for (int nf = 0; nf < 4; nf++) {
            int pc = lr + nf * 16;
#pragma unroll
            for (int r = 0; r < 4; r++) {
                int prr = g * 4 + r;
                pw[prr * 64 + (((pc >> 3) ^ (prr & 7)) * 8) + (pc & 7)] = f2bf(s[nf][r]);
            }
        }
#pragma unroll
        for (int ks = 0; ks < 2; ks++) {
            bf16x8 pa = *(const bf16x8*)(pw + lr * 64 + (((ks * 4 + g) ^ h3) * 8));
#pragma unroll
            for (int nh = 0; nh < 4; nh++) {
                int vr = lr + nh * 16;
                bf16x8 vf = *(const bf16x8*)(Vt + vr * 64 + (((ks * 4 + g) ^ h3) * 8));
                oacc[nh] = __builtin_amdgcn_mfma_f32_16x16x32_bf16(pa, vf, oacc[nh], 0, 0, 0);
            }
        }
        __syncthreads();
    }
#pragma unroll
    for (int r = 0; r < 4; r++) {
        float inv = 1.f / lrun[r];
        size_t orow = (size_t)(b * 512 + qbase + w * 16 + g * 4 + r) * 1024 + h * 64;
#pragma unroll
        for (int nh = 0; nh < 4; nh++)
            o[orow + lr + nh * 16] = f2bf(oacc[nh][r] * inv);
    }
}

// ---------- LayerNorm, bf16 in -> bf16 out (row = 1024) ----------
__global__ __launch_bounds__(256) void k_ln_b(const unsigned short* __restrict__ in,
                                              const float* __restrict__ gamma,
                                              const float* __restrict__ beta,
                                              unsigned short* __restrict__ outb) {
    int row = blockIdx.x, tid = threadIdx.x;
    u16x4 raw = *(const u16x4*)(in + (size_t)row * 1024 + tid * 4);
    float v0 = bf2f(raw[0]), v1 = bf2f(raw[1]), v2 = bf2f(raw[2]), v3 = bf2f(raw[3]);
    float s = v0 + v1 + v2 + v3;
    float q = v0 * v0 + v1 * v1 + v2 * v2 + v3 * v3;
#pragma unroll
    for (int d = 1; d < 64; d <<= 1) { s += __shfl_xor(s, d, 64); q += __shfl_xor(q, d, 64); }
    __shared__ float red[8];
    int l = tid & 63, w = tid >> 6;
    if (l == 0) { red[w] = s; red[4 + w] = q; }
    __syncthreads();
    s = red[0] + red[1] + red[2] + red[3];
    q = red[4] + red[5] + red[6] + red[7];
    float mu = s * (1.f / 1024.f);
    float var = q * (1.f / 1024.f) - mu * mu;
    float rstd = rsqrtf(var + 1e-5f);
    float4 g4 = *(const float4*)(gamma + tid * 4);
    float4 b4 = *(const float4*)(beta + tid * 4);
    u16x4 ob;
    ob[0] = f2bf((v0 - mu) * rstd * g4.x + b4.x);
    ob[1] = f2bf((v1 - mu) * rstd * g4.y + b4.y);
    ob[2] = f2bf((v2 - mu) * rstd * g4.z + b4.z);
    ob[3] = f2bf((v3 - mu) * rstd * g4.w + b4.w);
    *(u16x4*)(outb + (size_t)row * 1024 + tid * 4) = ob;
}

// ---------- LayerNorm, bf16 in -> f32 out (row = 1024) ----------
__global__ __launch_bounds__(256) void k_ln_bf(const unsigned short* __restrict__ in,
                                               const float* __restrict__ gamma,
                                               const float* __restrict__ beta,
                                               float* __restrict__ outf) {
    int row = blockIdx.x, tid = threadIdx.x;
    u16x4 raw = *(const u16x4*)(in + (size_t)row * 1024 + tid * 4);
    float v0 = bf2f(raw[0]), v1 = bf2f(raw[1]), v2 = bf2f(raw[2]), v3 = bf2f(raw[3]);
    float s = v0 + v1 + v2 + v3;
    float q = v0 * v0 + v1 * v1 + v2 * v2 + v3 * v3;
#pragma unroll
    for (int d = 1; d < 64; d <<= 1) { s += __shfl_xor(s, d, 64); q += __shfl_xor(q, d, 64); }
    __shared__ float red[8];
    int l = tid & 63, w = tid >> 6;
    if (l == 0) { red[w] = s; red[4 + w] = q; }
    __syncthreads();
    s = red[0] + red[1] + red[2] + red[3];
    q = red[4] + red[5] + red[6] + red[7];
    float mu = s * (1.f / 1024.f);
    float var = q * (1.f / 1024.f) - mu * mu;
    float rstd = rsqrtf(var + 1e-5f);
    float4 g4 = *(const float4*)(gamma + tid * 4);
    float4 b4 = *(const float4*)(beta + tid * 4);
    float4 y;
    y.x = (v0 - mu) * rstd * g4.x + b4.x;
    y.y = (v1 - mu) * rstd * g4.y + b4.y;
    y.z = (v2 - mu) * rstd * g4.z + b4.z;
    y.w = (v3 - mu) * rstd * g4.w + b4.w;
    *(float4*)(outf + (size_t)row * 1024 + tid * 4) = y;
}

// ---------- host launch ----------
extern "C" void kernel_launch(void* const* d_in, const int* in_sizes, int n_in,
                              void* d_out, int out_size, void* d_ws, size_t ws_size,
                              hipStream_t stream) {
    const float* x    = (const float*)d_in[0];
    const float* w_q  = (const float*)d_in[1];
    const float* b_q  = (const float*)d_in[2];
    const float* a_q  = (const float*)d_in[3];
    const float* bb_q = (const float*)d_in[4];
    const float* w_k  = (const float*)d_in[5];
    const float* b_k  = (const float*)d_in[6];
    const float* a_k  = (const float*)d_in[7];
    const float* bb_k = (const float*)d_in[8];
    const float* w_v  = (const float*)d_in[9];
    const float* b_v  = (const float*)d_in[10];
    const float* a_v  = (const float*)d_in[11];
    const float* bb_v = (const float*)d_in[12];
    const float* w_o  = (const float*)d_in[13];
    const float* b_o  = (const float*)d_in[14];
    const float* a_o  = (const float*)d_in[15];
    const float* bb_o = (const float*)d_in[16];
    const float* nw1  = (const float*)d_in[17];
    const float* nb1  = (const float*)d_in[18];
    const float* w_up = (const float*)d_in[19];
    const float* b_up = (const float*)d_in[20];
    const float* a_up = (const float*)d_in[21];
    const float* bb_up= (const float*)d_in[22];
    const float* w_dn = (const float*)d_in[23];
    const float* b_dn = (const float*)d_in[24];
    const float* a_dn = (const float*)d_in[25];
    const float* bb_dn= (const float*)d_in[26];
    const float* nw2  = (const float*)d_in[27];
    const float* nb2  = (const float*)d_in[28];
    const float* mask = (const float*)d_in[29];
    float* out = (float*)d_out;

    char* W = (char*)d_ws;
    size_t off = 0;
    auto alloc = [&](size_t bytes) { size_t r = off; off += (bytes + 1023) & ~(size_t)1023; return r; };

    unsigned short* WT_QKV = (unsigned short*)(W + alloc(3072ull * 1024 * 2));
    unsigned short* WT_O   = (unsigned short*)(W + alloc(1024ull * 1024 * 2));
    unsigned short* WT_UP  = (unsigned short*)(W + alloc(4096ull * 1024 * 2));
    unsigned short* WT_DN  = (unsigned short*)(W + alloc(1024ull * 4096 * 2));
    float* BIAS_QKV        = (float*)(W + alloc(3072ull * 4));
    unsigned short* XBF    = (unsigned short*)(W + alloc(8192ull * 1024 * 2)); // x bf16, later xm bf16
    unsigned short* BIG    = (unsigned short*)(W + alloc(8192ull * 4096 * 2)); // qkv, later fn
    unsigned short* O_BF   = (unsigned short*)(W + alloc(8192ull * 1024 * 2));
    unsigned short* OFB    = (unsigned short*)(W + alloc(8192ull * 1024 * 2)); // o_final bf16
    unsigned short* DNB    = (unsigned short*)(W + alloc(8192ull * 1024 * 2)); // down-out bf16
    (void)ws_size; (void)in_sizes; (void)n_in; (void)out_size;

    unsigned short* QKV = BIG;                 // [8192][3072]
    unsigned short* FN  = BIG;                 // [8192][4096]
    unsigned short* XMB = XBF;                 // x_medium bf16 (reuse)

    // 1) fused prep: x->bf16, 6 LoRA-folded weight transposes, bias concat (one launch)
    {
        PrepArgs pa{};
        int base = 0, i = 0;
        auto add = [&](const float* src, const float* a, const float* bb,
                       unsigned short* dst, int R, int C, int ds, int type) {
            int cnt;
            if (type == 0) cnt = (R * C) / (256 * 8);
            else if (type == 3) cnt = ((C + 31) / 32) * ((R + 31) / 32);
            else cnt = 12;
            pa.d[i] = {src, a, bb, dst, R, C, ds, (type == 3) ? (C + 31) / 32 : 1, base, type};
            base += cnt; i++;
        };
        add(x, nullptr, nullptr, XBF, 8192, 1024, 0, 0);
        add(w_q, a_q, bb_q, WT_QKV, 1024, 1024, 1024, 3);
        add(w_k, a_k, bb_k, WT_QKV + 1024ull * 1024, 1024, 1024, 1024, 3);
        add(w_v, a_v, bb_v, WT_QKV + 2048ull * 1024, 1024, 1024, 1024, 3);
        add(w_o, a_o, bb_o, WT_O, 1024, 1024, 1024, 3);
        add(w_up, a_up, bb_up, WT_UP, 1024, 4096, 1024, 3);
        add(w_dn, a_dn, bb_dn, WT_DN, 4096, 1024, 4096, 3);
        add(nullptr, nullptr, nullptr, nullptr, 0, 0, 0, 2);  // bias concat
        pa.nd = i;
        pa.bq = b_q; pa.bk = b_k; pa.bv = b_v; pa.bias_out = BIAS_QKV;
        k_prep<<<dim3(base), dim3(256), 0, stream>>>(pa);
    }
    // 2) QKV GEMM (gridDim.x=24 > 8 -> natural)
    {
        GemmArgs ga{XBF, WT_QKV, BIAS_QKV, nullptr, nullptr, nullptr, QKV,
                    8192, 3072, 1024, 0};
        k_gemm<0, false, true><<<dim3(24, 64), dim3(256), 0, stream>>>(ga);
    }
    // 3) attention
    k_attn<<<dim3(8, 256), dim3(256), 0, stream>>>(QKV, mask, O_BF);
    // 4) o_final(bf16) = o@W_O' + b_o + x  (gridDim.x=8 -> chunk swizzle)
    {
        GemmArgs ga{O_BF, WT_O, b_o, x, nullptr, nullptr, OFB,
                    8192, 1024, 1024, 1};
        k_gemm<1, false, true><<<dim3(8, 64), dim3(256), 0, stream>>>(ga);
    }
    // 5) LN1: bf16 in -> XMB bf16
    k_ln_b<<<dim3(8192), dim3(256), 0, stream>>>(OFB, nw1, nb1, XMB);
    // 6) up path (gridDim.x=32 > 8 -> natural)
    {
        GemmArgs ga{XMB, WT_UP, b_up, nullptr, nullptr, nullptr, FN,
                    8192, 4096, 1024, 0};
        k_gemm<0, true, true><<<dim3(32, 64), dim3(256), 0, stream>>>(ga);
    }
    // 7) down path (gridDim.x=8 -> chunk swizzle); residual = XMB bf16; output DNB bf16
    {
        GemmArgs ga{FN, WT_DN, b_dn, nullptr, XMB, nullptr, DNB,
                    8192, 1024, 4096, 1};
        k_gemm<2, false, true><<<dim3(8, 64), dim3(256), 0, stream>>>(ga);
    }
    // 8) LN2: bf16 in -> out (f32)
    k_ln_bf<<<dim3(8192), dim3(256), 0, stream>>>(DNB, nw2, nb2, out);
}